// Round 3
// baseline (988.690 us; speedup 1.0000x reference)
//
#include <hip/hip_runtime.h>
#include <math.h>

#define NQ_   32
#define M_    32
#define ND_   200
#define N_    160
#define H_    768
#define DIM_  128
#define DROWS_ (ND_ * N_)          // 32000
#define QROWS_ (NQ_ * M_)          // 1024
#define TROWS_ (DROWS_ + QROWS_)   // 33024

// async global->LDS, 16B per lane: LDS dest = wave-uniform base + lane*16
__device__ __forceinline__ void gl_lds16(const float* g, float* l) {
    __builtin_amdgcn_global_load_lds(
        (const __attribute__((address_space(1))) unsigned int*)g,
        (__attribute__((address_space(3))) unsigned int*)l, 16, 0, 0);
}

// ---------------------------------------------------------------------------
// Merged projection: 48 rows x 128 cols per 64-thread block (grid 688).
// Per-lane 12x8 tile: rg=lane&3 owns row pairs rg*2+8*ii (+0/1), cg=lane>>2
// owns col pairs cg*2+32*jj (+0/1). All LDS reads are b64 broadcasts
// (conflict-free); W staged via global_load_lds; stores are float2 over n
// (32B segments). Output transposed: DpT[d][k][n], QpT[q][k][m].
// ---------------------------------------------------------------------------
__global__ __launch_bounds__(64, 3) void proj_kernel(
    const float* __restrict__ Dmat, const float* __restrict__ Qmat,
    const float* __restrict__ W, float* __restrict__ DpT,
    float* __restrict__ QpT)
{
    __shared__ float Xt[8][48];     // [k][row]
    __shared__ float Ws[8][128];    // [k][col]
    const int lane  = threadIdx.x;
    const int rg    = lane & 3;
    const int cg    = lane >> 2;    // 0..15
    const int rbase = blockIdx.x * 48;

    float acc[12][8];               // [rg-pair rows][cg-pair cols]
#pragma unroll
    for (int i = 0; i < 12; ++i)
#pragma unroll
        for (int j = 0; j < 8; ++j) acc[i][j] = 0.0f;

    for (int kc = 0; kc < H_; kc += 8) {
        // stage X chunk: 48 rows x 8 k = 96 float4, transposed into Xt
#pragma unroll
        for (int it = 0; it < 2; ++it) {
            int idx = it * 64 + lane;
            if (idx < 96) {
                int row = idx >> 1, kh = idx & 1;
                int r = rbase + row;
                const float* xr = (r < DROWS_) ? (Dmat + (size_t)r * H_)
                                               : (Qmat + (size_t)(r - DROWS_) * H_);
                float4 v = *reinterpret_cast<const float4*>(xr + kc + kh * 4);
                Xt[kh*4+0][row] = v.x;
                Xt[kh*4+1][row] = v.y;
                Xt[kh*4+2][row] = v.z;
                Xt[kh*4+3][row] = v.w;
            }
        }
        // stage W chunk: rows kc..kc+7 are 4KB contiguous in W
#pragma unroll
        for (int c = 0; c < 4; ++c)
            gl_lds16(W + (size_t)kc * DIM_ + c * 256 + lane * 4, &Ws[0][0] + c * 256);
        __syncthreads();
#pragma unroll
        for (int k = 0; k < 8; ++k) {
            float a[12], b[8];
#pragma unroll
            for (int ii = 0; ii < 6; ++ii)
                *reinterpret_cast<float2*>(&a[ii*2]) =
                    *reinterpret_cast<const float2*>(&Xt[k][rg*2 + 8*ii]);
#pragma unroll
            for (int jj = 0; jj < 4; ++jj)
                *reinterpret_cast<float2*>(&b[jj*2]) =
                    *reinterpret_cast<const float2*>(&Ws[k][cg*2 + 32*jj]);
#pragma unroll
            for (int i = 0; i < 12; ++i)
#pragma unroll
                for (int j = 0; j < 8; ++j)
                    acc[i][j] = fmaf(a[i], b[j], acc[i][j]);
        }
        __syncthreads();
    }

    // normalize + transposed store. Row r's 128 cols live across the 16 cg
    // lanes (stride-4 lanes) -> butterfly xor {4,8,16,32}.
#pragma unroll
    for (int ii = 0; ii < 6; ++ii) {
        float nr[2];
#pragma unroll
        for (int p = 0; p < 2; ++p) {
            float ss = 0.0f;
#pragma unroll
            for (int j = 0; j < 8; ++j)
                ss = __fadd_rn(ss, __fmul_rn(acc[ii*2+p][j], acc[ii*2+p][j]));
            ss = __fadd_rn(ss, __shfl_xor(ss, 4));
            ss = __fadd_rn(ss, __shfl_xor(ss, 8));
            ss = __fadd_rn(ss, __shfl_xor(ss, 16));
            ss = __fadd_rn(ss, __shfl_xor(ss, 32));
            nr[p] = fmaxf(sqrtf(ss), 1e-12f);
        }
        const int r0 = rbase + rg*2 + 8*ii;   // even; pair r0,r0+1 never
                                              // crosses a 160/32/32000 boundary
        float* base; int stride;
        if (r0 < DROWS_) {
            int dd = r0 / 160, n = r0 - dd * 160;
            base = DpT + (size_t)dd * (DIM_ * N_) + n; stride = N_;
        } else {
            int rq = r0 - DROWS_;
            int qq = rq >> 5, m = rq & 31;
            base = QpT + (size_t)qq * (DIM_ * M_) + m; stride = M_;
        }
#pragma unroll
        for (int jj = 0; jj < 4; ++jj)
#pragma unroll
            for (int pc = 0; pc < 2; ++pc) {
                int c = cg*2 + 32*jj + pc;
                float2 v;
                v.x = acc[ii*2+0][jj*2+pc] / nr[0];
                v.y = acc[ii*2+1][jj*2+pc] / nr[1];
                *reinterpret_cast<float2*>(base + (size_t)c * stride) = v;
            }
    }
}

// ---------------------------------------------------------------------------
// Score: 128-thread block = 2 waves. Wave w handles q = qb*2+w; both waves
// share one d-pair (d = 2*dp, 2*dp+1). Per-lane 16x10 tile:
//   mg=lane>>5 -> rows mg*16..+15; ng=lane&31 -> (d'=ng>>4, cols (ng&15)*10..+9)
// Ratio 6(t+u)/tu = 0.975 -> VALU-bound. Staging via global_load_lds.
// ---------------------------------------------------------------------------
__global__ __launch_bounds__(128, 2) void score_kernel(
    const float* __restrict__ QpT, const float* __restrict__ DpT,
    const float* __restrict__ qmask, const float* __restrict__ dmask,
    const float* __restrict__ gum, float* __restrict__ out)
{
    __shared__ float Dt[2][8][160];   // [d'][k][n], 10 KB
    __shared__ float Qt[2][8][32];    // [wave][k][m], 2 KB
    const int tid  = threadIdx.x;
    const int w    = tid >> 6;
    const int lane = tid & 63;
    const int mg   = lane >> 5;       // 0..1
    const int ng   = lane & 31;
    const int dpr  = ng >> 4;         // d' in pair
    const int nn   = ng & 15;
    const int qb   = blockIdx.x & 15;
    const int dp   = blockIdx.x >> 4; // 0..99  (q-fast for DpT L2 reuse)
    const int q    = qb * 2 + w;
    const int d    = dp * 2 + dpr;

    const float* Qb  = QpT + (size_t)q * (DIM_ * M_);
    const float* Db0 = DpT + (size_t)(dp * 2) * (DIM_ * N_);

    float acc[16][10];
#pragma unroll
    for (int i = 0; i < 16; ++i)
#pragma unroll
        for (int j = 0; j < 10; ++j) acc[i][j] = 0.0f;

    for (int kc = 0; kc < DIM_; kc += 8) {
        // Qt: wave w stages its own q chunk (8x32 = 256 floats, one call)
        gl_lds16(Qb + kc * M_ + lane * 4, &Qt[w][0][0]);
        // Dt: 2 d' x 1280 floats = 10 segs of 256; wave w takes s = 2*it+w
#pragma unroll
        for (int it = 0; it < 5; ++it) {
            int s  = it * 2 + w;
            int sd = (s >= 5) ? 1 : 0;
            int so = s - sd * 5;
            gl_lds16(Db0 + (size_t)sd * (DIM_ * N_) + kc * N_ + so * 256 + lane * 4,
                     &Dt[0][0][0] + s * 256);
        }
        __syncthreads();
#pragma unroll
        for (int k = 0; k < 8; ++k) {
            float a[16], b[10];
#pragma unroll
            for (int c = 0; c < 4; ++c)
                *reinterpret_cast<float4*>(&a[c*4]) =
                    *reinterpret_cast<const float4*>(&Qt[w][k][mg*16 + c*4]);
            const float* bp = &Dt[dpr][k][nn*10];
#pragma unroll
            for (int j2 = 0; j2 < 5; ++j2)
                *reinterpret_cast<float2*>(&b[j2*2]) =
                    *reinterpret_cast<const float2*>(&bp[j2*2]);
#pragma unroll
            for (int i = 0; i < 16; ++i)
#pragma unroll
                for (int j = 0; j < 10; ++j)
                    acc[i][j] = fmaf(a[i], b[j], acc[i][j]);
        }
        __syncthreads();
    }

    float dmv[10];
#pragma unroll
    for (int j = 0; j < 10; ++j)
        dmv[j] = dmask[(size_t)d * N_ + nn*10 + j];

    const float* gq = gum + ((size_t)q * ND_ + d) * ((size_t)M_ * N_);

    float p0 = 0.0f, p1 = 0.0f;
#pragma unroll
    for (int i = 0; i < 16; ++i) {
        const int m = mg*16 + i;
        float x[10];
        float mx = -3.402823466e38f;
#pragma unroll
        for (int j = 0; j < 10; ++j) {
            float sm = (dmv[j] != 0.0f) ? acc[i][j] : -10000.0f;
            x[j] = sm / 0.1f;                 // IEEE divide: bit-matches np
            mx = fmaxf(mx, x[j]);
        }
        mx = fmaxf(mx, __shfl_xor(mx, 1));
        mx = fmaxf(mx, __shfl_xor(mx, 2));
        mx = fmaxf(mx, __shfl_xor(mx, 4));
        mx = fmaxf(mx, __shfl_xor(mx, 8));

        float se = 0.0f;
#pragma unroll
        for (int j = 0; j < 10; ++j) se = __fadd_rn(se, expf(x[j] - mx));
        se = __fadd_rn(se, __shfl_xor(se, 1));
        se = __fadd_rn(se, __shfl_xor(se, 2));
        se = __fadd_rn(se, __shfl_xor(se, 4));
        se = __fadd_rn(se, __shfl_xor(se, 8));
        const float lse = logf(se);

        float g[10];
        const float2* gp = reinterpret_cast<const float2*>(&gq[(size_t)m * N_ + nn*10]);
#pragma unroll
        for (int j2 = 0; j2 < 5; ++j2)
            *reinterpret_cast<float2*>(&g[j2*2]) = gp[j2];

        float z[10];
        float mz = -3.402823466e38f;
#pragma unroll
        for (int j = 0; j < 10; ++j) {
            z[j] = ((x[j] - mx - lse) + g[j]) / 0.5f;   // /0.5 == *2 exact
            mz = fmaxf(mz, z[j]);
        }
        mz = fmaxf(mz, __shfl_xor(mz, 1));
        mz = fmaxf(mz, __shfl_xor(mz, 2));
        mz = fmaxf(mz, __shfl_xor(mz, 4));
        mz = fmaxf(mz, __shfl_xor(mz, 8));

        float e2[10];
        float s2 = 0.0f;
#pragma unroll
        for (int j = 0; j < 10; ++j) { e2[j] = expf(z[j] - mz); s2 = __fadd_rn(s2, e2[j]); }
        s2 = __fadd_rn(s2, __shfl_xor(s2, 1));
        s2 = __fadd_rn(s2, __shfl_xor(s2, 2));
        s2 = __fadd_rn(s2, __shfl_xor(s2, 4));
        s2 = __fadd_rn(s2, __shfl_xor(s2, 8));

        // argmax of y_soft = e2/s2 with numpy first-index tie-break
        float besty = -1.0f; int bestn = 0x7fffffff; float bests = 0.0f;
#pragma unroll
        for (int j = 0; j < 10; ++j) {
            float y = e2[j] / s2;
            if (y > besty) {
                besty = y;
                bestn = nn*10 + j;
                bests = (dmv[j] != 0.0f) ? acc[i][j] : -10000.0f;
            }
        }
#pragma unroll
        for (int dl = 1; dl < 16; dl <<= 1) {
            float oy = __shfl_xor(besty, dl);
            int   on = __shfl_xor(bestn, dl);
            float os = __shfl_xor(bests, dl);
            if (oy > besty || (oy == besty && on < bestn)) {
                besty = oy; bestn = on; bests = os;
            }
        }
        const float qmv = qmask[q * M_ + m];
        float contrib = __fmul_rn(bests, qmv);
        if (i < 8) p0 = __fadd_rn(p0, contrib);
        else       p1 = __fadd_rn(p1, contrib);
    }
    // lane(mg0): (rows 0-7)+(8-15); lane(mg1): (16-23)+(24-31); xor32 combines
    // -> exact numpy pairwise order for 32 elements.
    float partial = __fadd_rn(p0, p1);
    partial = __fadd_rn(partial, __shfl_xor(partial, 32));
    if (nn == 0 && mg == 0)
        out[(size_t)q * ND_ + d] = partial;
}

// ---------------------------------------------------------------------------
extern "C" void kernel_launch(void* const* d_in, const int* in_sizes, int n_in,
                              void* d_out, int out_size, void* d_ws, size_t ws_size,
                              hipStream_t stream)
{
    const float* Q   = (const float*)d_in[0];   // (32,32,768)
    const float* D   = (const float*)d_in[1];   // (200,160,768)
    const float* qm  = (const float*)d_in[2];   // (32,32)
    const float* dm  = (const float*)d_in[3];   // (200,160)
    const float* gum = (const float*)d_in[4];   // (32,200,32,160)
    const float* W   = (const float*)d_in[5];   // (768,128)
    float* out = (float*)d_out;                 // (32,200)

    float* QpT = (float*)d_ws;                          // 32*128*32
    float* DpT = QpT + (size_t)QROWS_ * DIM_;           // 200*128*160

    proj_kernel<<<dim3(TROWS_ / 48), dim3(64), 0, stream>>>(D, Q, W, DpT, QpT);
    score_kernel<<<dim3((NQ_ / 2) * (ND_ / 2)), dim3(128), 0, stream>>>(QpT, DpT, qm, dm, gum, out);
}